// Round 1
// baseline (118.010 us; speedup 1.0000x reference)
//
#include <hip/hip_runtime.h>

// AnalyticalBoundedLineAttractor — exact linear-regime stepping via Taylor
// recurrence:
//   z = Wx + b; m_dt = (z>0)?dt:0
//   w1 = m_dt*z - dt*x;  wk = (m_dt*(W w) - dt*w)/k;  x+ = x + sum wk
// ||Z|| <= dt*(||W||_2+1) ~ 0.15 -> K=3 terms, local truncation ~2e-5/step,
// accumulated ~6e-3 (threshold 7.7e-2; non-expansive dynamics, no blowup).
//
// Matvec: broadcast form. Lane i holds row i of W in 64 VGPRs (natural
// order). w_j is broadcast to all lanes via v_readlane (SGPR), and lane i
// accumulates v_i = sum_j Wr[j]*w_j locally — no cross-lane reduction, no
// LDS, no barriers, and the 64 readlanes are mutually INDEPENDENT (unlike
// a serial DPP rotate chain). 4 interleaved accumulators give 16-cyc
// dep-reuse gaps >> 4-cyc FMA latency.
//
// R0 (this session): defensive launch fix only. Prior session verified this
// body at 118.6 us; this bench aborted (core dump, no counters). Suspect
// in_sizes unit mismatch (bytes vs elements) quadrupling the grid -> OOB
// writes -> GPU fault. Grid is now clamped to the problem's fixed batch=256
// so the launch cannot exceed the output buffer regardless of units.

#define DT_F 0.05f
#define T_STEPS 100
#define DD 64
#define KT 3  // Taylor terms w_1..w_KT
#define BATCH_MAX 256

__device__ __forceinline__ float matvec64(const float (&Wr)[DD], float w) {
    const int wi = __float_as_int(w);
    float a0 = 0.f, a1 = 0.f, a2 = 0.f, a3 = 0.f;
#pragma unroll
    for (int j = 0; j < DD; j += 4) {
        const float s0 = __int_as_float(__builtin_amdgcn_readlane(wi, j + 0));
        const float s1 = __int_as_float(__builtin_amdgcn_readlane(wi, j + 1));
        const float s2 = __int_as_float(__builtin_amdgcn_readlane(wi, j + 2));
        const float s3 = __int_as_float(__builtin_amdgcn_readlane(wi, j + 3));
        a0 = fmaf(Wr[j + 0], s0, a0);
        a1 = fmaf(Wr[j + 1], s1, a1);
        a2 = fmaf(Wr[j + 2], s2, a2);
        a3 = fmaf(Wr[j + 3], s3, a3);
    }
    return (a0 + a1) + (a2 + a3);
}

__global__ __launch_bounds__(64, 1)
void abla_kernel(const float* __restrict__ x0,
                 const float* __restrict__ W,
                 const float* __restrict__ bvec,
                 float* __restrict__ out) {
    const int batch = blockIdx.x;
    const int lane = threadIdx.x;

    // Lane i caches row i of W (natural order) in 64 VGPRs. One-time load;
    // stride-256B across lanes is uncoalesced but only ~147 KB total fetch.
    float Wr[DD];
#pragma unroll
    for (int j = 0; j < DD; j += 4) {
        const float4 w4 = *reinterpret_cast<const float4*>(W + lane * DD + j);
        Wr[j + 0] = w4.x; Wr[j + 1] = w4.y; Wr[j + 2] = w4.z; Wr[j + 3] = w4.w;
    }
    const float bi = bvec[lane];
    float x = x0[batch * DD + lane];
    float* outp = out + (size_t)batch * T_STEPS * DD + lane;

    for (int t = 0; t < T_STEPS; ++t) {
        // Trajectory stores the state BEFORE the update (off critical path).
        outp[(size_t)t * DD] = x;

        // term 1: z = Wx + b gives the regime mask
        const float z = matvec64(Wr, x) + bi;
        const float m_dt = (z > 0.f) ? DT_F : 0.f;
        float w = m_dt * z - DT_F * x;
        float y = x + w;

        // terms 2..KT
#pragma unroll
        for (int k = 2; k <= KT; ++k) {
            const float v = matvec64(Wr, w);
            w = (m_dt * v - DT_F * w) * (1.0f / (float)k);
            y += w;
        }
        x = y;
    }
}

extern "C" void kernel_launch(void* const* d_in, const int* in_sizes, int n_in,
                              void* d_out, int out_size, void* d_ws, size_t ws_size,
                              hipStream_t stream) {
    const float* x0 = (const float*)d_in[0];   // (256, 64) f32
    const float* W  = (const float*)d_in[1];   // (64, 64)  f32
    const float* b  = (const float*)d_in[2];   // (64,)     f32
    float* out = (float*)d_out;                // (256, 100, 64) f32

    // Problem shape is fixed (batch=256, dim=64). Derive batch from
    // in_sizes[0] when it is a plausible element count; clamp otherwise so a
    // bytes-vs-elements unit mismatch can never launch an OOB grid.
    int batch = in_sizes[0] / DD;
    if (batch <= 0 || batch > BATCH_MAX) batch = BATCH_MAX;
    abla_kernel<<<batch, DD, 0, stream>>>(x0, W, b, out);
}